// Round 1
// baseline (48902.222 us; speedup 1.0000x reference)
//
#include <hip/hip_runtime.h>
#include <math.h>

// ---------------------------------------------------------------------------
// 4-layer stacked GRU, B=256, T=1024, sizes (1->256)(256->128)(128->128)(128->256)
// Round 1: correctness-first persistent kernel. One workgroup (256 thr) per
// batch element; entire 4-layer recurrence + output projection in one kernel.
// Weights pre-transposed to [in_dim][3H] so gate index is the fast (coalesced)
// axis for the per-step matvecs. Expected L2-BW bound (~774 GB of weight
// re-reads over the 1024 steps).
// ---------------------------------------------------------------------------

__device__ __forceinline__ float sigmoidf_(float v) {
    return 1.0f / (1.0f + __expf(-v));
}

// src[rows][cols] -> dst[cols][rows]   (dst[c*rows + r] = src[r*cols + c])
__global__ void transpose_k(const float* __restrict__ src, float* __restrict__ dst,
                            int rows, int cols) {
    int idx = blockIdx.x * 256 + threadIdx.x;
    if (idx < rows * cols) {
        int r = idx / cols;
        int c = idx - r * cols;
        dst[c * rows + r] = src[idx];
    }
}

__global__ __launch_bounds__(256) void gru_stack_kernel(
    const float* __restrict__ x,
    const float* __restrict__ w_ih1,  // [768] (in=1, so already [1][768] transposed)
    const float* __restrict__ b_ih1, const float* __restrict__ b_hh1,
    const float* __restrict__ b_ih2, const float* __restrict__ b_hh2,
    const float* __restrict__ b_ih3, const float* __restrict__ b_hh3,
    const float* __restrict__ b_ih4, const float* __restrict__ b_hh4,
    const float* __restrict__ wt_hh1,  // [256][768]
    const float* __restrict__ wt_ih2,  // [256][384]
    const float* __restrict__ wt_hh2,  // [128][384]
    const float* __restrict__ wt_ih3,  // [128][384]
    const float* __restrict__ wt_hh3,  // [128][384]
    const float* __restrict__ wt_ih4,  // [128][768]
    const float* __restrict__ wt_hh4,  // [256][768]
    const float* __restrict__ w_out,   // [256]
    const float* __restrict__ b_out,   // [1]
    float* __restrict__ out)           // [256][1024]
{
    const int tid = threadIdx.x;
    const int b   = blockIdx.x;

    __shared__ float h1[256], h2[128], h3[128], h4[256];
    __shared__ float gx[768], gh[768];
    __shared__ float red[4];

    h1[tid] = 0.0f;
    h4[tid] = 0.0f;
    if (tid < 128) { h2[tid] = 0.0f; h3[tid] = 0.0f; }
    __syncthreads();

    const float* xrow = x + (size_t)b * 1024;
    float* orow       = out + (size_t)b * 1024;

    for (int t = 0; t < 1024; ++t) {
        const float xv = xrow[t];

        // ----- layer 1: in=1 (scalar), H=256, 3H=768 -----
        {
            float a0 = b_ih1[tid]       + xv * w_ih1[tid];
            float a1 = b_ih1[tid + 256] + xv * w_ih1[tid + 256];
            float a2 = b_ih1[tid + 512] + xv * w_ih1[tid + 512];
            float c0 = b_hh1[tid], c1 = b_hh1[tid + 256], c2 = b_hh1[tid + 512];
            #pragma unroll 8
            for (int j = 0; j < 256; ++j) {
                const float hv = h1[j];
                const float* wr = wt_hh1 + j * 768;
                c0 += hv * wr[tid];
                c1 += hv * wr[tid + 256];
                c2 += hv * wr[tid + 512];
            }
            gx[tid] = a0; gx[tid + 256] = a1; gx[tid + 512] = a2;
            gh[tid] = c0; gh[tid + 256] = c1; gh[tid + 512] = c2;
        }
        __syncthreads();
        {
            const float r = sigmoidf_(gx[tid] + gh[tid]);
            const float z = sigmoidf_(gx[256 + tid] + gh[256 + tid]);
            const float n = tanhf(gx[512 + tid] + r * gh[512 + tid]);
            h1[tid] = (1.0f - z) * n + z * h1[tid];
        }
        __syncthreads();

        // ----- layer 2: in=256 (h1), H=128, 3H=384 -----
        {
            float a0 = b_ih2[tid];
            float c0 = b_hh2[tid];
            #pragma unroll 8
            for (int j = 0; j < 256; ++j) a0 += h1[j] * wt_ih2[j * 384 + tid];
            #pragma unroll 8
            for (int j = 0; j < 128; ++j) c0 += h2[j] * wt_hh2[j * 384 + tid];
            gx[tid] = a0; gh[tid] = c0;
            if (tid < 128) {
                float a1 = b_ih2[tid + 256];
                float c1 = b_hh2[tid + 256];
                #pragma unroll 8
                for (int j = 0; j < 256; ++j) a1 += h1[j] * wt_ih2[j * 384 + 256 + tid];
                #pragma unroll 8
                for (int j = 0; j < 128; ++j) c1 += h2[j] * wt_hh2[j * 384 + 256 + tid];
                gx[tid + 256] = a1; gh[tid + 256] = c1;
            }
        }
        __syncthreads();
        if (tid < 128) {
            const float r = sigmoidf_(gx[tid] + gh[tid]);
            const float z = sigmoidf_(gx[128 + tid] + gh[128 + tid]);
            const float n = tanhf(gx[256 + tid] + r * gh[256 + tid]);
            h2[tid] = (1.0f - z) * n + z * h2[tid];
        }
        __syncthreads();

        // ----- layer 3: in=128 (h2), H=128, 3H=384 -----
        {
            float a0 = b_ih3[tid];
            float c0 = b_hh3[tid];
            #pragma unroll 8
            for (int j = 0; j < 128; ++j) a0 += h2[j] * wt_ih3[j * 384 + tid];
            #pragma unroll 8
            for (int j = 0; j < 128; ++j) c0 += h3[j] * wt_hh3[j * 384 + tid];
            gx[tid] = a0; gh[tid] = c0;
            if (tid < 128) {
                float a1 = b_ih3[tid + 256];
                float c1 = b_hh3[tid + 256];
                #pragma unroll 8
                for (int j = 0; j < 128; ++j) a1 += h2[j] * wt_ih3[j * 384 + 256 + tid];
                #pragma unroll 8
                for (int j = 0; j < 128; ++j) c1 += h3[j] * wt_hh3[j * 384 + 256 + tid];
                gx[tid + 256] = a1; gh[tid + 256] = c1;
            }
        }
        __syncthreads();
        if (tid < 128) {
            const float r = sigmoidf_(gx[tid] + gh[tid]);
            const float z = sigmoidf_(gx[128 + tid] + gh[128 + tid]);
            const float n = tanhf(gx[256 + tid] + r * gh[256 + tid]);
            h3[tid] = (1.0f - z) * n + z * h3[tid];
        }
        __syncthreads();

        // ----- layer 4: in=128 (h3), H=256, 3H=768 -----
        {
            float a0 = b_ih4[tid], a1 = b_ih4[tid + 256], a2 = b_ih4[tid + 512];
            float c0 = b_hh4[tid], c1 = b_hh4[tid + 256], c2 = b_hh4[tid + 512];
            #pragma unroll 8
            for (int j = 0; j < 128; ++j) {
                const float hv = h3[j];
                const float* wr = wt_ih4 + j * 768;
                a0 += hv * wr[tid];
                a1 += hv * wr[tid + 256];
                a2 += hv * wr[tid + 512];
            }
            #pragma unroll 8
            for (int j = 0; j < 256; ++j) {
                const float hv = h4[j];
                const float* wr = wt_hh4 + j * 768;
                c0 += hv * wr[tid];
                c1 += hv * wr[tid + 256];
                c2 += hv * wr[tid + 512];
            }
            gx[tid] = a0; gx[tid + 256] = a1; gx[tid + 512] = a2;
            gh[tid] = c0; gh[tid + 256] = c1; gh[tid + 512] = c2;
        }
        __syncthreads();
        {
            const float r = sigmoidf_(gx[tid] + gh[tid]);
            const float z = sigmoidf_(gx[256 + tid] + gh[256 + tid]);
            const float n = tanhf(gx[512 + tid] + r * gh[512 + tid]);
            h4[tid] = (1.0f - z) * n + z * h4[tid];
        }
        __syncthreads();

        // ----- output projection: y = dot(w_out, h4) + b_out -----
        {
            float p = w_out[tid] * h4[tid];
            #pragma unroll
            for (int off = 32; off > 0; off >>= 1) p += __shfl_down(p, off, 64);
            if ((tid & 63) == 0) red[tid >> 6] = p;
            __syncthreads();
            if (tid == 0) orow[t] = red[0] + red[1] + red[2] + red[3] + b_out[0];
        }
        // next iteration's first write to h* is after a __syncthreads(); gx/gh
        // overwrites don't alias red/h4 reads above, so no extra barrier needed.
    }
}

extern "C" void kernel_launch(void* const* d_in, const int* in_sizes, int n_in,
                              void* d_out, int out_size, void* d_ws, size_t ws_size,
                              hipStream_t stream) {
    const float* x     = (const float*)d_in[0];
    const float* w_ih1 = (const float*)d_in[1];
    const float* w_hh1 = (const float*)d_in[2];
    const float* b_ih1 = (const float*)d_in[3];
    const float* b_hh1 = (const float*)d_in[4];
    const float* w_ih2 = (const float*)d_in[5];
    const float* w_hh2 = (const float*)d_in[6];
    const float* b_ih2 = (const float*)d_in[7];
    const float* b_hh2 = (const float*)d_in[8];
    const float* w_ih3 = (const float*)d_in[9];
    const float* w_hh3 = (const float*)d_in[10];
    const float* b_ih3 = (const float*)d_in[11];
    const float* b_hh3 = (const float*)d_in[12];
    const float* w_ih4 = (const float*)d_in[13];
    const float* w_hh4 = (const float*)d_in[14];
    const float* b_ih4 = (const float*)d_in[15];
    const float* b_hh4 = (const float*)d_in[16];
    const float* w_out = (const float*)d_in[17];
    const float* b_out = (const float*)d_in[18];

    float* ws = (float*)d_ws;
    float* wt_hh1 = ws;                 // 256*768
    float* wt_ih2 = wt_hh1 + 196608;    // 256*384
    float* wt_hh2 = wt_ih2 + 98304;     // 128*384
    float* wt_ih3 = wt_hh2 + 49152;     // 128*384
    float* wt_hh3 = wt_ih3 + 49152;     // 128*384
    float* wt_ih4 = wt_hh3 + 49152;     // 128*768
    float* wt_hh4 = wt_ih4 + 98304;     // 256*768  (total 737280 floats ~ 2.95 MB)

    auto tr = [&](const float* s, float* d, int rows, int cols) {
        int n = rows * cols;
        transpose_k<<<(n + 255) / 256, 256, 0, stream>>>(s, d, rows, cols);
    };
    tr(w_hh1, wt_hh1, 768, 256);
    tr(w_ih2, wt_ih2, 384, 256);
    tr(w_hh2, wt_hh2, 384, 128);
    tr(w_ih3, wt_ih3, 384, 128);
    tr(w_hh3, wt_hh3, 384, 128);
    tr(w_ih4, wt_ih4, 768, 128);
    tr(w_hh4, wt_hh4, 768, 256);

    gru_stack_kernel<<<256, 256, 0, stream>>>(
        x, w_ih1, b_ih1, b_hh1, b_ih2, b_hh2, b_ih3, b_hh3, b_ih4, b_hh4,
        wt_hh1, wt_ih2, wt_hh2, wt_ih3, wt_hh3, wt_ih4, wt_hh4,
        w_out, b_out, (float*)d_out);
}